// Round 8
// baseline (84.471 us; speedup 1.0000x reference)
//
#include <hip/hip_runtime.h>
#include <math.h>

#define BN 4
#define CN 64
#define HN 64
#define WN 256
#define ON 64
#define NOC 18
#define PN 9
#define HO 31
#define WO 127

// LDS V: 32 pixels x 328 shorts (5 taps x 64 ch + 8 pad) = 20992 B
#define VST 328   // shorts per pixel
#define VSB 656   // bytes per pixel

typedef __attribute__((ext_vector_type(8))) short bf16x8;
typedef __attribute__((ext_vector_type(4))) float f32x4;

__device__ __forceinline__ unsigned short f2bf(float f) {
    unsigned int u = __float_as_uint(f);
    unsigned int r = (u + 0x7fffu + ((u >> 16) & 1u)) >> 16;
    return (unsigned short)r;
}

__device__ __forceinline__ float trianglewave(float x) {
    const float PI_F = 3.14159274101257324f;   // float(np.pi)
    float n = floorf(x / PI_F + 0.5f);
    float m = fmodf(n, 2.0f);
    if (m < 0.0f) m += 2.0f;
    float sgn = 1.0f - 2.0f * m;
    return (x - PI_F * n) * sgn;
}

__device__ __forceinline__ float prak_f(float x) {
    const float PI_HALF = 1.57079637050628662f; // float(np.pi/2)
    return trianglewave(x) + trianglewave(x + PI_HALF);
}

// blocks 0..4095: x[b][c][h][w] -> x_t[b][h][w][c]
// blocks 4096..4239: weight prep (Wf: 4 m-tiles, WoF: 2 m-tiles, fragment order)
__global__ __launch_bounds__(256) void prep_transpose_kernel(
        const float* __restrict__ x,
        const float* __restrict__ offw,
        const float* __restrict__ wgt,
        float* __restrict__ xt,
        unsigned short* __restrict__ Wf,
        unsigned short* __restrict__ WoF) {
    if (blockIdx.x < 4096) {
        int T = blockIdx.x * 256 + threadIdx.x;
        int g = T & 15;
        int w = (T >> 4) & 255;
        int h = (T >> 12) & 63;
        int b = T >> 18;
        float4 v;
        int c0 = g * 4;
        v.x = x[((size_t)(b * CN + c0 + 0) * HN + h) * WN + w];
        v.y = x[((size_t)(b * CN + c0 + 1) * HN + h) * WN + w];
        v.z = x[((size_t)(b * CN + c0 + 2) * HN + h) * WN + w];
        v.w = x[((size_t)(b * CN + c0 + 3) * HN + h) * WN + w];
        *(float4*)(xt + (((size_t)(b * HN) + h) * WN + w) * 64 + c0) = v;
    } else {
        int t = (blockIdx.x - 4096) * 256 + threadIdx.x;
        if (t < 4 * 18 * 64 * 8) {
            int j    = t & 7;
            int lane = (t >> 3) & 63;
            int rest = t >> 9;          // 0..71
            int ks   = rest % 18;
            int m    = rest / 18;
            int o = m * 16 + (lane & 15);
            int k = ks * 32 + (lane >> 4) * 8 + j;
            int c = k & 63;
            int p = k >> 6;
            Wf[t] = f2bf(wgt[(o * CN + c) * 9 + p]);
        }
        if (t < 2 * 18 * 64 * 8) {
            int j    = t & 7;
            int lane = (t >> 3) & 63;
            int rest = t >> 9;          // 0..35
            int ks   = rest % 18;
            int mo   = rest / 18;
            int o = mo * 16 + (lane & 15);
            int k = ks * 32 + (lane >> 4) * 8 + j;
            int c = k & 63;
            int p = k >> 6;
            WoF[t] = (o < NOC) ? f2bf(offw[(o * CN + c) * 9 + p]) : (unsigned short)0;
        }
    }
}

// Fully fused, split-K: {im2col, offsMFMA} x2 -> {gather, defMFMA} x2.
// 512 threads = 8 waves per 32-pixel tile; grid 2048 XCD-swizzled.
// LDS ~23.4 KB -> 4 blocks/CU = 32 waves/CU.
__global__ __launch_bounds__(512, 8) void fused_kernel(
        const float* __restrict__ xt,
        const float* __restrict__ offb,
        const float* __restrict__ mask,
        const unsigned short* __restrict__ WoF,
        const unsigned short* __restrict__ Wf,
        float* __restrict__ y,
        float2* __restrict__ partials) {
    __shared__ __align__(16) unsigned short V[32 * VST];   // 20992 B
    __shared__ float offs_lds[NOC * 32];                   // 2304 B
    __shared__ float red1[8], red2[8];

    int bid = blockIdx.x;
    int logical = ((bid & 7) << 8) + (bid >> 3);   // 8 XCDs x 256-chunk
    int wtile = logical & 7;          // 8 w-tiles of 32 pixels
    int h = (logical >> 3) & 63;
    int b = logical >> 9;
    int lane = threadIdx.x & 63;
    int wv = threadIdx.x >> 6;        // 0..7

    int pl = threadIdx.x >> 4;        // 0..31  (pixel)
    int cg = threadIdx.x & 15;        // 0..15  (channel quad)
    int w = (wtile << 5) + pl;
    const float* xb = xt + ((size_t)(b * HN) * WN) * 64;

    int pixc = (wv & 1) * 16 + (lane & 15);   // pixel col for MFMA phases
    int kq = lane >> 4;

    // persistent accumulators
    f32x4 acc_off = {0.0f, 0.0f, 0.0f, 0.0f};   // waves 0..3
    f32x4 acc     = {0.0f, 0.0f, 0.0f, 0.0f};   // deform, all waves

    // ================= half 1: taps 0..4 (ks 0..9) =================
#pragma unroll
    for (int p = 0; p < 5; p++) {
        int iy = h + p / 3 - 1;
        int ix = w + p % 3 - 1;
        uint2 pk = {0u, 0u};
        if (iy >= 0 && iy < HN && ix >= 0 && ix < WN) {
            float4 v0 = *(const float4*)(xb + ((size_t)iy * WN + ix) * 64 + cg * 4);
            pk.x = ((unsigned int)f2bf(v0.y) << 16) | (unsigned int)f2bf(v0.x);
            pk.y = ((unsigned int)f2bf(v0.w) << 16) | (unsigned int)f2bf(v0.z);
        }
        *(uint2*)((char*)V + pl * VSB + p * 128 + cg * 8) = pk;
    }
    __syncthreads();

    if (wv < 4) {                 // offsets MFMA, ks 0..9
        int mo = wv >> 1;
        const bf16x8* Wov = (const bf16x8*)WoF;
#pragma unroll
        for (int ks = 0; ks < 10; ks++) {
            bf16x8 a = Wov[(mo * 18 + ks) * 64 + lane];
            bf16x8 bfr = *(const bf16x8*)((char*)V + pixc * VSB + ks * 64 + kq * 16);
            acc_off = __builtin_amdgcn_mfma_f32_16x16x32_bf16(a, bfr, acc_off, 0, 0, 0);
        }
    }
    __syncthreads();

    // ================= half 2: taps 5..8 (ks 10..17) =================
#pragma unroll
    for (int p = 5; p < 9; p++) {
        int iy = h + p / 3 - 1;
        int ix = w + p % 3 - 1;
        uint2 pk = {0u, 0u};
        if (iy >= 0 && iy < HN && ix >= 0 && ix < WN) {
            float4 v0 = *(const float4*)(xb + ((size_t)iy * WN + ix) * 64 + cg * 4);
            pk.x = ((unsigned int)f2bf(v0.y) << 16) | (unsigned int)f2bf(v0.x);
            pk.y = ((unsigned int)f2bf(v0.w) << 16) | (unsigned int)f2bf(v0.z);
        }
        *(uint2*)((char*)V + pl * VSB + (p - 5) * 128 + cg * 8) = pk;
    }
    __syncthreads();

    if (wv < 4) {                 // offsets MFMA, ks 10..17, then emit offsets
        int mo = wv >> 1;
        const bf16x8* Wov = (const bf16x8*)WoF;
#pragma unroll
        for (int ks = 0; ks < 8; ks++) {
            bf16x8 a = Wov[(mo * 18 + 10 + ks) * 64 + lane];
            bf16x8 bfr = *(const bf16x8*)((char*)V + pixc * VSB + ks * 64 + kq * 16);
            acc_off = __builtin_amdgcn_mfma_f32_16x16x32_bf16(a, bfr, acc_off, 0, 0, 0);
        }
        int ocb = mo * 16 + kq * 4;
#pragma unroll
        for (int r = 0; r < 4; r++) {
            int oc = ocb + r;
            if (oc < NOC) offs_lds[oc * 32 + pixc] = acc_off[r] + offb[oc];
        }
    }
    __syncthreads();

    // ================= deform halves =================
#pragma unroll
    for (int half = 0; half < 2; half++) {
        int tapLo = half ? 5 : 0;
        int nTaps = half ? 4 : 5;
        // gather taps -> V
        for (int pp = 0; pp < nTaps; pp++) {
            int p = tapLo + pp;
            float offy = offs_lds[(2 * p) * 32 + pl];
            float offx = offs_lds[(2 * p + 1) * 32 + pl];
            float mk   = mask[((b * PN + p) * HN + h) * WN + w];

            float py = (float)(h + p / 3) + offy;   // padded space
            float px = (float)(w + p % 3) + offx;
            float fy0 = floorf(py);
            float fx0 = floorf(px);
            float wy1 = py - fy0, wx1 = px - fx0;
            float wy0 = 1.0f - wy1, wx0 = 1.0f - wx1;

            int iy0 = (int)fy0 - 1;   // x-space top-left
            int ix0 = (int)fx0 - 1;
            int iy1 = iy0 + 1, ix1 = ix0 + 1;
            bool vy0 = (iy0 >= 0) && (iy0 < HN);
            bool vy1 = (iy1 >= 0) && (iy1 < HN);
            bool vx0 = (ix0 >= 0) && (ix0 < WN);
            bool vx1 = (ix1 >= 0) && (ix1 < WN);

            float w00 = (vy0 && vx0) ? wy0 * wx0 * mk : 0.0f;
            float w01 = (vy0 && vx1) ? wy0 * wx1 * mk : 0.0f;
            float w10 = (vy1 && vx0) ? wy1 * wx0 * mk : 0.0f;
            float w11 = (vy1 && vx1) ? wy1 * wx1 * mk : 0.0f;

            int cy0 = min(max(iy0, 0), HN - 1), cy1 = min(max(iy1, 0), HN - 1);
            int cx0 = min(max(ix0, 0), WN - 1), cx1 = min(max(ix1, 0), WN - 1);

            float4 A = *(const float4*)(xb + ((size_t)cy0 * WN + cx0) * 64 + cg * 4);
            float4 B = *(const float4*)(xb + ((size_t)cy0 * WN + cx1) * 64 + cg * 4);
            float4 C = *(const float4*)(xb + ((size_t)cy1 * WN + cx0) * 64 + cg * 4);
            float4 D = *(const float4*)(xb + ((size_t)cy1 * WN + cx1) * 64 + cg * 4);

            float v0 = w00 * A.x + w01 * B.x + w10 * C.x + w11 * D.x;
            float v1 = w00 * A.y + w01 * B.y + w10 * C.y + w11 * D.y;
            float v2 = w00 * A.z + w01 * B.z + w10 * C.z + w11 * D.z;
            float v3 = w00 * A.w + w01 * B.w + w10 * C.w + w11 * D.w;

            uint2 pk;
            pk.x = ((unsigned int)f2bf(v1) << 16) | (unsigned int)f2bf(v0);
            pk.y = ((unsigned int)f2bf(v3) << 16) | (unsigned int)f2bf(v2);
            *(uint2*)((char*)V + pl * VSB + pp * 128 + cg * 8) = pk;
        }
        __syncthreads();

        // deform MFMA over this half's ks
        {
            int m = wv >> 1;
            int ksBase = half ? 10 : 0;
            int nKs = half ? 8 : 10;
            const bf16x8* Wfv = (const bf16x8*)Wf;
            for (int ks = 0; ks < nKs; ks++) {
                bf16x8 a = Wfv[(m * 18 + ksBase + ks) * 64 + lane];
                bf16x8 bfr = *(const bf16x8*)((char*)V + pixc * VSB + ks * 64 + kq * 16);
                acc = __builtin_amdgcn_mfma_f32_16x16x32_bf16(a, bfr, acc, 0, 0, 0);
            }
        }
        if (half == 0) __syncthreads();
    }

    // ================= epilogue: write y + partial stats =================
    int m = wv >> 1;
    int orow = m * 16 + kq * 4;
    float s1 = 0.0f, s2 = 0.0f;
#pragma unroll
    for (int r = 0; r < 4; r++) {
        float v0 = acc[r];
        y[(((size_t)(b * ON + orow + r) * HN) + h) * WN + (wtile << 5) + pixc] = v0;
        s1 += v0;
        s2 += v0 * v0;
    }
#pragma unroll
    for (int off = 32; off > 0; off >>= 1) {
        s1 += __shfl_down(s1, off);
        s2 += __shfl_down(s2, off);
    }
    if (lane == 0) { red1[wv] = s1; red2[wv] = s2; }
    __syncthreads();
    if (threadIdx.x == 0) {
        float t1 = 0.0f, t2 = 0.0f;
#pragma unroll
        for (int i = 0; i < 8; i++) { t1 += red1[i]; t2 += red2[i]; }
        partials[blockIdx.x] = make_float2(t1, t2);
    }
}

__global__ __launch_bounds__(256) void stats_kernel(const float2* __restrict__ partials,
                                                    int nblocks,
                                                    float* __restrict__ stats) {
    __shared__ double r1[256], r2[256];
    int tid = threadIdx.x;
    double s1 = 0.0, s2 = 0.0;
    for (int i = tid; i < nblocks; i += 256) {
        s1 += (double)partials[i].x;
        s2 += (double)partials[i].y;
    }
    r1[tid] = s1;
    r2[tid] = s2;
    __syncthreads();
    for (int s = 128; s > 0; s >>= 1) {
        if (tid < s) { r1[tid] += r1[tid + s]; r2[tid] += r2[tid + s]; }
        __syncthreads();
    }
    if (tid == 0) {
        double N = (double)BN * ON * HN * WN;
        double mu = r1[0] / N;
        double var = r2[0] / N - mu * mu;
        stats[0] = (float)mu;
        stats[1] = (float)(1.0 / sqrt(var + 1e-5));
    }
}

// normalize + prak + concat(x) + 3x3/2 maxpool
__global__ __launch_bounds__(256) void out_kernel(const float* __restrict__ yb,
                                                  const float* __restrict__ x,
                                                  const float* __restrict__ stats,
                                                  float* __restrict__ out) {
    int t = blockIdx.x * 256 + threadIdx.x;
    if (t >= BN * 128 * HO * WO) return;
    int ow = t % WO;
    int oh = (t / WO) % HO;
    int ch = (t / (WO * HO)) % 128;
    int b  = t / (WO * HO * 128);

    float mu = stats[0];
    float inv = stats[1];
    float m = -INFINITY;
    if (ch < 64) {
        const float* yc = yb + ((size_t)(b * ON + ch) * HN) * WN;
#pragma unroll
        for (int dy = 0; dy < 3; dy++) {
            const float* row = yc + (2 * oh + dy) * WN + 2 * ow;
#pragma unroll
            for (int dx = 0; dx < 3; dx++) {
                float v = prak_f((row[dx] - mu) * inv);
                m = fmaxf(m, v);
            }
        }
    } else {
        const float* xc = x + ((size_t)(b * CN + (ch - 64)) * HN) * WN;
#pragma unroll
        for (int dy = 0; dy < 3; dy++) {
            const float* row = xc + (2 * oh + dy) * WN + 2 * ow;
#pragma unroll
            for (int dx = 0; dx < 3; dx++) m = fmaxf(m, row[dx]);
        }
    }
    out[t] = m;
}

extern "C" void kernel_launch(void* const* d_in, const int* in_sizes, int n_in,
                              void* d_out, int out_size, void* d_ws, size_t ws_size,
                              hipStream_t stream) {
    const float* x    = (const float*)d_in[0];
    const float* offw = (const float*)d_in[1];
    const float* offb = (const float*)d_in[2];
    const float* wgt  = (const float*)d_in[3];
    const float* mask = (const float*)d_in[4];
    float* out = (float*)d_out;

    float* ws = (float*)d_ws;
    unsigned short* Wf  = (unsigned short*)ws;            // 36864 bf16
    unsigned short* WoF = Wf + 36864;                     // 18432 bf16
    float* y  = (float*)(WoF + 18432 + 2048);             // align; 4194304 f
    float* xt = y + 4194304;                              // 4194304 f
    float2* partials = (float2*)(xt + 4194304);           // 2048 float2
    float* stats = (float*)(partials + 2048);             // 2 f

    prep_transpose_kernel<<<4240, 256, 0, stream>>>(x, offw, wgt, xt, Wf, WoF);
    fused_kernel<<<2048, 512, 0, stream>>>(xt, offb, mask, WoF, Wf, y, partials);
    stats_kernel<<<1, 256, 0, stream>>>(partials, 2048, stats);
    out_kernel<<<7874, 256, 0, stream>>>(y, x, stats, out);
}

// Round 9
// 78.247 us; speedup vs baseline: 1.0795x; 1.0795x over previous
//
#include <hip/hip_runtime.h>
#include <math.h>

#define BN 4
#define CN 64
#define HN 64
#define WN 256
#define ON 64
#define NOC 18
#define PN 9
#define HO 31
#define WO 127

// LDS V (half-K): 64 pixels x 328 shorts (5 taps x 64 ch + 8 pad) = 41984 B
#define VST 328   // shorts per pixel
#define VSB 656   // bytes per pixel

typedef __attribute__((ext_vector_type(8))) short bf16x8;
typedef __attribute__((ext_vector_type(4))) float f32x4;

__device__ __forceinline__ unsigned short f2bf(float f) {
    unsigned int u = __float_as_uint(f);
    unsigned int r = (u + 0x7fffu + ((u >> 16) & 1u)) >> 16;
    return (unsigned short)r;
}

__device__ __forceinline__ float trianglewave(float x) {
    const float PI_F = 3.14159274101257324f;   // float(np.pi)
    float n = floorf(x / PI_F + 0.5f);
    float m = fmodf(n, 2.0f);
    if (m < 0.0f) m += 2.0f;
    float sgn = 1.0f - 2.0f * m;
    return (x - PI_F * n) * sgn;
}

__device__ __forceinline__ float prak_f(float x) {
    const float PI_HALF = 1.57079637050628662f; // float(np.pi/2)
    return trianglewave(x) + trianglewave(x + PI_HALF);
}

// blocks 0..4095: x[b][c][h][w] -> x_t[b][h][w][c]
// blocks 4096..4239: weight prep (Wf: 4 m-tiles, WoF: 2 m-tiles, fragment order)
__global__ __launch_bounds__(256) void prep_transpose_kernel(
        const float* __restrict__ x,
        const float* __restrict__ offw,
        const float* __restrict__ wgt,
        float* __restrict__ xt,
        unsigned short* __restrict__ Wf,
        unsigned short* __restrict__ WoF) {
    if (blockIdx.x < 4096) {
        int T = blockIdx.x * 256 + threadIdx.x;
        int g = T & 15;
        int w = (T >> 4) & 255;
        int h = (T >> 12) & 63;
        int b = T >> 18;
        float4 v;
        int c0 = g * 4;
        v.x = x[((size_t)(b * CN + c0 + 0) * HN + h) * WN + w];
        v.y = x[((size_t)(b * CN + c0 + 1) * HN + h) * WN + w];
        v.z = x[((size_t)(b * CN + c0 + 2) * HN + h) * WN + w];
        v.w = x[((size_t)(b * CN + c0 + 3) * HN + h) * WN + w];
        *(float4*)(xt + (((size_t)(b * HN) + h) * WN + w) * 64 + c0) = v;
    } else {
        int t = (blockIdx.x - 4096) * 256 + threadIdx.x;
        if (t < 4 * 18 * 64 * 8) {
            int j    = t & 7;
            int lane = (t >> 3) & 63;
            int rest = t >> 9;          // 0..71
            int ks   = rest % 18;
            int m    = rest / 18;
            int o = m * 16 + (lane & 15);
            int k = ks * 32 + (lane >> 4) * 8 + j;
            int c = k & 63;
            int p = k >> 6;
            Wf[t] = f2bf(wgt[(o * CN + c) * 9 + p]);
        }
        if (t < 2 * 18 * 64 * 8) {
            int j    = t & 7;
            int lane = (t >> 3) & 63;
            int rest = t >> 9;          // 0..35
            int ks   = rest % 18;
            int mo   = rest / 18;
            int o = mo * 16 + (lane & 15);
            int k = ks * 32 + (lane >> 4) * 8 + j;
            int c = k & 63;
            int p = k >> 6;
            WoF[t] = (o < NOC) ? f2bf(offw[(o * CN + c) * 9 + p]) : (unsigned short)0;
        }
    }
}

// Fully fused, split-K with 64-pixel tiles (R6 shape, half-size V):
// {im2col, offsMFMA} x2 -> {gather, defMFMA} x2, register accs persist.
// 512 threads = 8 waves; grid 1024 XCD-swizzled; LDS ~46.7 KB -> 3 blocks/CU.
__global__ __launch_bounds__(512, 6) void fused_kernel(
        const float* __restrict__ xt,
        const float* __restrict__ offb,
        const float* __restrict__ mask,
        const unsigned short* __restrict__ WoF,
        const unsigned short* __restrict__ Wf,
        float* __restrict__ y,
        float2* __restrict__ partials) {
    __shared__ __align__(16) unsigned short V[64 * VST];   // 41984 B
    __shared__ float offs_lds[NOC * 64];                   // 4608 B
    __shared__ float red1[8], red2[8];

    int bid = blockIdx.x;
    int logical = ((bid & 7) << 7) + (bid >> 3);   // 8 XCDs x 128-chunk
    int b = logical >> 8;
    int h = (logical >> 2) & 63;
    int wblk = logical & 3;
    int lane = threadIdx.x & 63;
    int wv = threadIdx.x >> 6;        // 0..7

    int pl = threadIdx.x >> 3;        // 0..63  (pixel, staging)
    int cg = threadIdx.x & 7;         // 0..7   (8 channels, staging)
    int w = (wblk << 6) + pl;
    const float* xb = xt + ((size_t)(b * HN) * WN) * 64;

    int kq = lane >> 4;

    // persistent accumulators
    f32x4 acc_off = {0.0f, 0.0f, 0.0f, 0.0f};           // offsets (all 8 waves)
    f32x4 acc0 = {0.0f, 0.0f, 0.0f, 0.0f};             // deform N-tile a
    f32x4 acc1 = {0.0f, 0.0f, 0.0f, 0.0f};             // deform N-tile b

    int pixcO = (wv & 3) * 16 + (lane & 15);           // offsets-phase pixel col
    int pixcD = (wv & 1) * 32 + (lane & 15);           // deform-phase pixel col

    // ================= offsets halves: im2col + offMFMA =================
#pragma unroll
    for (int half = 0; half < 2; half++) {
        int tapLo = half ? 5 : 0;
        int tapHi = half ? 9 : 5;
#pragma unroll
        for (int p = tapLo; p < tapHi; p++) {
            int iy = h + p / 3 - 1;
            int ix = w + p % 3 - 1;
            uint4 pk = {0u, 0u, 0u, 0u};
            if (iy >= 0 && iy < HN && ix >= 0 && ix < WN) {
                const float4* src = (const float4*)(xb + ((size_t)iy * WN + ix) * 64 + cg * 8);
                float4 v0 = src[0], v1 = src[1];
                pk.x = ((unsigned int)f2bf(v0.y) << 16) | (unsigned int)f2bf(v0.x);
                pk.y = ((unsigned int)f2bf(v0.w) << 16) | (unsigned int)f2bf(v0.z);
                pk.z = ((unsigned int)f2bf(v1.y) << 16) | (unsigned int)f2bf(v1.x);
                pk.w = ((unsigned int)f2bf(v1.w) << 16) | (unsigned int)f2bf(v1.z);
            }
            *(uint4*)((char*)V + pl * VSB + (p - tapLo) * 128 + cg * 16) = pk;
        }
        __syncthreads();

        {
            int mo = wv >> 2;                 // 0..1
            int ksBase = half ? 10 : 0;
            int nKs = half ? 8 : 10;
            const bf16x8* Wov = (const bf16x8*)WoF;
            for (int ks = 0; ks < nKs; ks++) {
                bf16x8 a = Wov[(mo * 18 + ksBase + ks) * 64 + lane];
                bf16x8 bfr = *(const bf16x8*)((char*)V + pixcO * VSB + ks * 64 + kq * 16);
                acc_off = __builtin_amdgcn_mfma_f32_16x16x32_bf16(a, bfr, acc_off, 0, 0, 0);
            }
        }
        __syncthreads();
    }

    // emit offsets to LDS
    {
        int mo = wv >> 2;
        int ocb = mo * 16 + kq * 4;
#pragma unroll
        for (int r = 0; r < 4; r++) {
            int oc = ocb + r;
            if (oc < NOC) offs_lds[oc * 64 + pixcO] = acc_off[r] + offb[oc];
        }
    }
    __syncthreads();

    // ================= deform halves: gather + defMFMA =================
#pragma unroll
    for (int half = 0; half < 2; half++) {
        int tapLo = half ? 5 : 0;
        int nTaps = half ? 4 : 5;
        for (int pp = 0; pp < nTaps; pp++) {
            int p = tapLo + pp;
            float offy = offs_lds[(2 * p) * 64 + pl];
            float offx = offs_lds[(2 * p + 1) * 64 + pl];
            float mk   = mask[((b * PN + p) * HN + h) * WN + w];

            float py = (float)(h + p / 3) + offy;   // padded space
            float px = (float)(w + p % 3) + offx;
            float fy0 = floorf(py);
            float fx0 = floorf(px);
            float wy1 = py - fy0, wx1 = px - fx0;
            float wy0 = 1.0f - wy1, wx0 = 1.0f - wx1;

            int iy0 = (int)fy0 - 1;   // x-space top-left
            int ix0 = (int)fx0 - 1;
            int iy1 = iy0 + 1, ix1 = ix0 + 1;
            bool vy0 = (iy0 >= 0) && (iy0 < HN);
            bool vy1 = (iy1 >= 0) && (iy1 < HN);
            bool vx0 = (ix0 >= 0) && (ix0 < WN);
            bool vx1 = (ix1 >= 0) && (ix1 < WN);

            float w00 = (vy0 && vx0) ? wy0 * wx0 * mk : 0.0f;
            float w01 = (vy0 && vx1) ? wy0 * wx1 * mk : 0.0f;
            float w10 = (vy1 && vx0) ? wy1 * wx0 * mk : 0.0f;
            float w11 = (vy1 && vx1) ? wy1 * wx1 * mk : 0.0f;

            int cy0 = min(max(iy0, 0), HN - 1), cy1 = min(max(iy1, 0), HN - 1);
            int cx0 = min(max(ix0, 0), WN - 1), cx1 = min(max(ix1, 0), WN - 1);

            const float4* p00 = (const float4*)(xb + ((size_t)cy0 * WN + cx0) * 64 + cg * 8);
            const float4* p01 = (const float4*)(xb + ((size_t)cy0 * WN + cx1) * 64 + cg * 8);
            const float4* p10 = (const float4*)(xb + ((size_t)cy1 * WN + cx0) * 64 + cg * 8);
            const float4* p11 = (const float4*)(xb + ((size_t)cy1 * WN + cx1) * 64 + cg * 8);

            float4 A0 = p00[0], A1 = p00[1];
            float4 B0 = p01[0], B1 = p01[1];
            float4 C0 = p10[0], C1 = p10[1];
            float4 D0 = p11[0], D1 = p11[1];

            float v0 = w00 * A0.x + w01 * B0.x + w10 * C0.x + w11 * D0.x;
            float v1 = w00 * A0.y + w01 * B0.y + w10 * C0.y + w11 * D0.y;
            float v2 = w00 * A0.z + w01 * B0.z + w10 * C0.z + w11 * D0.z;
            float v3 = w00 * A0.w + w01 * B0.w + w10 * C0.w + w11 * D0.w;
            float v4 = w00 * A1.x + w01 * B1.x + w10 * C1.x + w11 * D1.x;
            float v5 = w00 * A1.y + w01 * B1.y + w10 * C1.y + w11 * D1.y;
            float v6 = w00 * A1.z + w01 * B1.z + w10 * C1.z + w11 * D1.z;
            float v7 = w00 * A1.w + w01 * B1.w + w10 * C1.w + w11 * D1.w;

            uint4 pk;
            pk.x = ((unsigned int)f2bf(v1) << 16) | (unsigned int)f2bf(v0);
            pk.y = ((unsigned int)f2bf(v3) << 16) | (unsigned int)f2bf(v2);
            pk.z = ((unsigned int)f2bf(v5) << 16) | (unsigned int)f2bf(v4);
            pk.w = ((unsigned int)f2bf(v7) << 16) | (unsigned int)f2bf(v6);
            *(uint4*)((char*)V + pl * VSB + pp * 128 + cg * 16) = pk;
        }
        __syncthreads();

        {
            int m = wv >> 1;                  // 0..3
            int ksBase = half ? 10 : 0;
            int nKs = half ? 8 : 10;
            const bf16x8* Wfv = (const bf16x8*)Wf;
            for (int ks = 0; ks < nKs; ks++) {
                bf16x8 a  = Wfv[(m * 18 + ksBase + ks) * 64 + lane];
                bf16x8 b0 = *(const bf16x8*)((char*)V + pixcD * VSB + ks * 64 + kq * 16);
                bf16x8 b1 = *(const bf16x8*)((char*)V + (pixcD + 16) * VSB + ks * 64 + kq * 16);
                acc0 = __builtin_amdgcn_mfma_f32_16x16x32_bf16(a, b0, acc0, 0, 0, 0);
                acc1 = __builtin_amdgcn_mfma_f32_16x16x32_bf16(a, b1, acc1, 0, 0, 0);
            }
        }
        if (half == 0) __syncthreads();
    }

    // ================= epilogue: write y + partial stats =================
    int m = wv >> 1;
    int orow = m * 16 + kq * 4;
    float s1 = 0.0f, s2 = 0.0f;
#pragma unroll
    for (int r = 0; r < 4; r++) {
        float v0 = acc0[r];
        float v1 = acc1[r];
        size_t base = (((size_t)(b * ON + orow + r) * HN) + h) * WN + (wblk << 6);
        y[base + pixcD] = v0;
        y[base + pixcD + 16] = v1;
        s1 += v0 + v1;
        s2 += v0 * v0 + v1 * v1;
    }
#pragma unroll
    for (int off = 32; off > 0; off >>= 1) {
        s1 += __shfl_down(s1, off);
        s2 += __shfl_down(s2, off);
    }
    if (lane == 0) { red1[wv] = s1; red2[wv] = s2; }
    __syncthreads();
    if (threadIdx.x == 0) {
        float t1 = 0.0f, t2 = 0.0f;
#pragma unroll
        for (int i = 0; i < 8; i++) { t1 += red1[i]; t2 += red2[i]; }
        partials[blockIdx.x] = make_float2(t1, t2);
    }
}

__global__ __launch_bounds__(256) void stats_kernel(const float2* __restrict__ partials,
                                                    int nblocks,
                                                    float* __restrict__ stats) {
    __shared__ double r1[256], r2[256];
    int tid = threadIdx.x;
    double s1 = 0.0, s2 = 0.0;
    for (int i = tid; i < nblocks; i += 256) {
        s1 += (double)partials[i].x;
        s2 += (double)partials[i].y;
    }
    r1[tid] = s1;
    r2[tid] = s2;
    __syncthreads();
    for (int s = 128; s > 0; s >>= 1) {
        if (tid < s) { r1[tid] += r1[tid + s]; r2[tid] += r2[tid + s]; }
        __syncthreads();
    }
    if (tid == 0) {
        double N = (double)BN * ON * HN * WN;
        double mu = r1[0] / N;
        double var = r2[0] / N - mu * mu;
        stats[0] = (float)mu;
        stats[1] = (float)(1.0 / sqrt(var + 1e-5));
    }
}

// normalize + prak + concat(x) + 3x3/2 maxpool
__global__ __launch_bounds__(256) void out_kernel(const float* __restrict__ yb,
                                                  const float* __restrict__ x,
                                                  const float* __restrict__ stats,
                                                  float* __restrict__ out) {
    int t = blockIdx.x * 256 + threadIdx.x;
    if (t >= BN * 128 * HO * WO) return;
    int ow = t % WO;
    int oh = (t / WO) % HO;
    int ch = (t / (WO * HO)) % 128;
    int b  = t / (WO * HO * 128);

    float mu = stats[0];
    float inv = stats[1];
    float m = -INFINITY;
    if (ch < 64) {
        const float* yc = yb + ((size_t)(b * ON + ch) * HN) * WN;
#pragma unroll
        for (int dy = 0; dy < 3; dy++) {
            const float* row = yc + (2 * oh + dy) * WN + 2 * ow;
#pragma unroll
            for (int dx = 0; dx < 3; dx++) {
                float v = prak_f((row[dx] - mu) * inv);
                m = fmaxf(m, v);
            }
        }
    } else {
        const float* xc = x + ((size_t)(b * CN + (ch - 64)) * HN) * WN;
#pragma unroll
        for (int dy = 0; dy < 3; dy++) {
            const float* row = xc + (2 * oh + dy) * WN + 2 * ow;
#pragma unroll
            for (int dx = 0; dx < 3; dx++) m = fmaxf(m, row[dx]);
        }
    }
    out[t] = m;
}

extern "C" void kernel_launch(void* const* d_in, const int* in_sizes, int n_in,
                              void* d_out, int out_size, void* d_ws, size_t ws_size,
                              hipStream_t stream) {
    const float* x    = (const float*)d_in[0];
    const float* offw = (const float*)d_in[1];
    const float* offb = (const float*)d_in[2];
    const float* wgt  = (const float*)d_in[3];
    const float* mask = (const float*)d_in[4];
    float* out = (float*)d_out;

    float* ws = (float*)d_ws;
    unsigned short* Wf  = (unsigned short*)ws;            // 36864 bf16
    unsigned short* WoF = Wf + 36864;                     // 18432 bf16
    float* y  = (float*)(WoF + 18432 + 2048);             // align; 4194304 f
    float* xt = y + 4194304;                              // 4194304 f
    float2* partials = (float2*)(xt + 4194304);           // 1024 float2
    float* stats = (float*)(partials + 1024);             // 2 f

    prep_transpose_kernel<<<4240, 256, 0, stream>>>(x, offw, wgt, xt, Wf, WoF);
    fused_kernel<<<1024, 512, 0, stream>>>(xt, offb, mask, WoF, Wf, y, partials);
    stats_kernel<<<1, 256, 0, stream>>>(partials, 1024, stats);
    out_kernel<<<7874, 256, 0, stream>>>(y, x, stats, out);
}

// Round 10
// 68.442 us; speedup vs baseline: 1.2342x; 1.1433x over previous
//
#include <hip/hip_runtime.h>
#include <math.h>

#define BN 4
#define CN 64
#define HN 64
#define WN 256
#define ON 64
#define NOC 18
#define PN 9
#define HO 31
#define WO 127

// LDS V: 64 pixels x 584 shorts (9 taps x 64 ch + 8 pad) = 74752 B
#define VST 584   // shorts per pixel
#define VSB 1168  // bytes per pixel

typedef __attribute__((ext_vector_type(8))) short bf16x8;
typedef __attribute__((ext_vector_type(4))) float f32x4;

__device__ __forceinline__ unsigned short f2bf(float f) {
    unsigned int u = __float_as_uint(f);
    unsigned int r = (u + 0x7fffu + ((u >> 16) & 1u)) >> 16;
    return (unsigned short)r;
}

// packed bf16 convert: low16 = bf16(lo), high16 = bf16(hi)
__device__ __forceinline__ unsigned int cvtpk(float lo, float hi) {
    unsigned int r;
    asm("v_cvt_pk_bf16_f32 %0, %1, %2" : "=v"(r) : "v"(lo), "v"(hi));
    return r;
}

__device__ __forceinline__ float trianglewave(float x) {
    const float PI_F = 3.14159274101257324f;   // float(np.pi)
    float n = floorf(x / PI_F + 0.5f);
    float m = fmodf(n, 2.0f);
    if (m < 0.0f) m += 2.0f;
    float sgn = 1.0f - 2.0f * m;
    return (x - PI_F * n) * sgn;
}

__device__ __forceinline__ float prak_f(float x) {
    const float PI_HALF = 1.57079637050628662f; // float(np.pi/2)
    return trianglewave(x) + trianglewave(x + PI_HALF);
}

// blocks 0..511: LDS-transposed x[b][c][h][w] -> x_t[b][h][w][c]  (b,h,whalf)
// blocks 512..583: weight prep (Wf: 4 m-tiles, WoF: 2 m-tiles, fragment order)
__global__ __launch_bounds__(512) void prep_transpose_kernel(
        const float* __restrict__ x,
        const float* __restrict__ offw,
        const float* __restrict__ wgt,
        float* __restrict__ xt,
        unsigned short* __restrict__ Wf,
        unsigned short* __restrict__ WoF) {
    if (blockIdx.x < 512) {
        __shared__ float Tl[128][65];
        int blk = blockIdx.x;
        int whalf = blk & 1;
        int h = (blk >> 1) & 63;
        int b = blk >> 7;
        int t = threadIdx.x;
        // read: coalesced rows of x
        int fq = t & 31;           // float4 index within 128-float half row
#pragma unroll
        for (int j = 0; j < 4; j++) {
            int c = (t >> 5) + 16 * j;
            float4 v = *(const float4*)(x + ((size_t)(b * CN + c) * HN + h) * WN + whalf * 128 + fq * 4);
            Tl[fq * 4 + 0][c] = v.x;
            Tl[fq * 4 + 1][c] = v.y;
            Tl[fq * 4 + 2][c] = v.z;
            Tl[fq * 4 + 3][c] = v.w;
        }
        __syncthreads();
        // write: coalesced rows of xt
        int cq = t & 15;
#pragma unroll
        for (int j = 0; j < 4; j++) {
            int wl = (t >> 4) + 32 * j;
            float4 o;
            o.x = Tl[wl][cq * 4 + 0];
            o.y = Tl[wl][cq * 4 + 1];
            o.z = Tl[wl][cq * 4 + 2];
            o.w = Tl[wl][cq * 4 + 3];
            *(float4*)(xt + (((size_t)(b * HN) + h) * WN + whalf * 128 + wl) * 64 + cq * 4) = o;
        }
    } else {
        int t = (blockIdx.x - 512) * 512 + threadIdx.x;
        if (t < 4 * 18 * 64 * 8) {
            int j    = t & 7;
            int lane = (t >> 3) & 63;
            int rest = t >> 9;          // 0..71
            int ks   = rest % 18;
            int m    = rest / 18;
            int o = m * 16 + (lane & 15);
            int k = ks * 32 + (lane >> 4) * 8 + j;
            int c = k & 63;
            int p = k >> 6;
            Wf[t] = f2bf(wgt[(o * CN + c) * 9 + p]);
        }
        if (t < 2 * 18 * 64 * 8) {
            int j    = t & 7;
            int lane = (t >> 3) & 63;
            int rest = t >> 9;          // 0..35
            int ks   = rest % 18;
            int mo   = rest / 18;
            int o = mo * 16 + (lane & 15);
            int k = ks * 32 + (lane >> 4) * 8 + j;
            int c = k & 63;
            int p = k >> 6;
            WoF[t] = (o < NOC) ? f2bf(offw[(o * CN + c) * 9 + p]) : (unsigned short)0;
        }
    }
}

struct TapS { float w00, w01, w10, w11; int a0, a1, a2, a3; };

// Fully fused (R6 structure): im2col -> offsets MFMA -> pipelined gather -> deform MFMA.
// 512 threads = 8 waves per 64-pixel tile; grid 1024 XCD-swizzled; 2 blocks/CU.
__global__ __launch_bounds__(512, 4) void fused_kernel(
        const float* __restrict__ xt,
        const float* __restrict__ offb,
        const float* __restrict__ mask,
        const unsigned short* __restrict__ WoF,
        const unsigned short* __restrict__ Wf,
        float* __restrict__ y,
        float2* __restrict__ partials) {
    __shared__ __align__(16) unsigned short V[64 * VST];   // 74752 B
    __shared__ float offs_lds[NOC * 64];                   // 4608 B
    __shared__ float red1[8], red2[8];

    int bid = blockIdx.x;
    int logical = ((bid & 7) << 7) + (bid >> 3);   // XCD-chunked
    int b = logical >> 8;
    int h = (logical >> 2) & 63;
    int wblk = logical & 3;
    int lane = threadIdx.x & 63;
    int wv = threadIdx.x >> 6;          // 0..7

    int pl = threadIdx.x >> 3;          // 0..63 (pixel, staging)
    int cg = threadIdx.x & 7;           // 0..7  (8 channels, staging)
    int w = (wblk << 6) + pl;
    const float* xb = xt + ((size_t)(b * HN) * WN) * 64;
    int kq = lane >> 4;

    // ---------- Phase 0: regular im2col (bf16) ----------
#pragma unroll
    for (int p = 0; p < PN; p++) {
        int iy = h + p / 3 - 1;
        int ix = w + p % 3 - 1;
        uint4 pk = {0u, 0u, 0u, 0u};
        if (iy >= 0 && iy < HN && ix >= 0 && ix < WN) {
            const float4* src = (const float4*)(xb + ((size_t)iy * WN + ix) * 64 + cg * 8);
            float4 v0 = src[0], v1 = src[1];
            pk.x = cvtpk(v0.x, v0.y);
            pk.y = cvtpk(v0.z, v0.w);
            pk.z = cvtpk(v1.x, v1.y);
            pk.w = cvtpk(v1.z, v1.w);
        }
        *(uint4*)((char*)V + pl * VSB + p * 128 + cg * 16) = pk;
    }
    __syncthreads();

    // ---------- Offsets MFMA: 18x576 @ 576x64 ----------
    {
        int mo = wv >> 2;       // 0..1
        int nt = wv & 3;        // 0..3
        f32x4 acc = {0.0f, 0.0f, 0.0f, 0.0f};
        const bf16x8* Wov = (const bf16x8*)WoF;
        int pixc = nt * 16 + (lane & 15);
#pragma unroll
        for (int ks = 0; ks < 18; ks++) {
            bf16x8 a = Wov[(mo * 18 + ks) * 64 + lane];
            bf16x8 bfr = *(const bf16x8*)((char*)V + pixc * VSB + ks * 64 + kq * 16);
            acc = __builtin_amdgcn_mfma_f32_16x16x32_bf16(a, bfr, acc, 0, 0, 0);
        }
        int ocb = mo * 16 + kq * 4;
#pragma unroll
        for (int r = 0; r < 4; r++) {
            int oc = ocb + r;
            if (oc < NOC) offs_lds[oc * 64 + pixc] = acc[r] + offb[oc];
        }
    }
    __syncthreads();

    // ---------- Phase 1: deformable gather (2-deep pipelined, overwrites V) ----------
    {
        const float4* xb4 = (const float4*)xb;   // index = (cy*WN+cx)*16 + cg*2

        float mkv[9];
#pragma unroll
        for (int p = 0; p < 9; p++) mkv[p] = mask[((b * PN + p) * HN + h) * WN + w];

        auto stage = [&](int p) -> TapS {
            TapS s;
            float offy = offs_lds[(2 * p) * 64 + pl];
            float offx = offs_lds[(2 * p + 1) * 64 + pl];
            float mk = mkv[p];
            float py = (float)(h + p / 3) + offy;   // padded space
            float px = (float)(w + p % 3) + offx;
            float fy0 = floorf(py), fx0 = floorf(px);
            float wy1 = py - fy0, wx1 = px - fx0;
            float wy0 = 1.0f - wy1, wx0 = 1.0f - wx1;
            int iy0 = (int)fy0 - 1, ix0 = (int)fx0 - 1;
            int iy1 = iy0 + 1, ix1 = ix0 + 1;
            bool vy0 = (iy0 >= 0) && (iy0 < HN);
            bool vy1 = (iy1 >= 0) && (iy1 < HN);
            bool vx0 = (ix0 >= 0) && (ix0 < WN);
            bool vx1 = (ix1 >= 0) && (ix1 < WN);
            s.w00 = (vy0 && vx0) ? wy0 * wx0 * mk : 0.0f;
            s.w01 = (vy0 && vx1) ? wy0 * wx1 * mk : 0.0f;
            s.w10 = (vy1 && vx0) ? wy1 * wx0 * mk : 0.0f;
            s.w11 = (vy1 && vx1) ? wy1 * wx1 * mk : 0.0f;
            int cy0 = min(max(iy0, 0), HN - 1), cy1 = min(max(iy1, 0), HN - 1);
            int cx0 = min(max(ix0, 0), WN - 1), cx1 = min(max(ix1, 0), WN - 1);
            s.a0 = (cy0 * WN + cx0) * 16 + cg * 2;
            s.a1 = (cy0 * WN + cx1) * 16 + cg * 2;
            s.a2 = (cy1 * WN + cx0) * 16 + cg * 2;
            s.a3 = (cy1 * WN + cx1) * 16 + cg * 2;
            return s;
        };

        TapS sC = stage(0);
        float4 A0 = xb4[sC.a0], A1 = xb4[sC.a0 + 1];
        float4 B0 = xb4[sC.a1], B1 = xb4[sC.a1 + 1];
        float4 C0 = xb4[sC.a2], C1 = xb4[sC.a2 + 1];
        float4 D0 = xb4[sC.a3], D1 = xb4[sC.a3 + 1];

#pragma unroll
        for (int p = 0; p < 9; p++) {
            TapS sN;
            float4 nA0, nA1, nB0, nB1, nC0, nC1, nD0, nD1;
            if (p < 8) {
                sN = stage(p + 1);
                nA0 = xb4[sN.a0]; nA1 = xb4[sN.a0 + 1];
                nB0 = xb4[sN.a1]; nB1 = xb4[sN.a1 + 1];
                nC0 = xb4[sN.a2]; nC1 = xb4[sN.a2 + 1];
                nD0 = xb4[sN.a3]; nD1 = xb4[sN.a3 + 1];
            }
            float v0 = sC.w00 * A0.x + sC.w01 * B0.x + sC.w10 * C0.x + sC.w11 * D0.x;
            float v1 = sC.w00 * A0.y + sC.w01 * B0.y + sC.w10 * C0.y + sC.w11 * D0.y;
            float v2 = sC.w00 * A0.z + sC.w01 * B0.z + sC.w10 * C0.z + sC.w11 * D0.z;
            float v3 = sC.w00 * A0.w + sC.w01 * B0.w + sC.w10 * C0.w + sC.w11 * D0.w;
            float v4 = sC.w00 * A1.x + sC.w01 * B1.x + sC.w10 * C1.x + sC.w11 * D1.x;
            float v5 = sC.w00 * A1.y + sC.w01 * B1.y + sC.w10 * C1.y + sC.w11 * D1.y;
            float v6 = sC.w00 * A1.z + sC.w01 * B1.z + sC.w10 * C1.z + sC.w11 * D1.z;
            float v7 = sC.w00 * A1.w + sC.w01 * B1.w + sC.w10 * C1.w + sC.w11 * D1.w;
            uint4 pk;
            pk.x = cvtpk(v0, v1);
            pk.y = cvtpk(v2, v3);
            pk.z = cvtpk(v4, v5);
            pk.w = cvtpk(v6, v7);
            *(uint4*)((char*)V + pl * VSB + p * 128 + cg * 16) = pk;
            if (p < 8) {
                sC = sN;
                A0 = nA0; A1 = nA1; B0 = nB0; B1 = nB1;
                C0 = nC0; C1 = nC1; D0 = nD0; D1 = nD1;
            }
        }
    }
    __syncthreads();

    // ---------- Phase 2: deform MFMA ----------
    int m = wv >> 1;            // M-tile 0..3
    int npair = wv & 1;         // N-tiles npair*2, npair*2+1
    f32x4 acc0 = {0.0f, 0.0f, 0.0f, 0.0f};
    f32x4 acc1 = {0.0f, 0.0f, 0.0f, 0.0f};
    const bf16x8* Wfv = (const bf16x8*)Wf;
    int pixc = npair * 32 + (lane & 15);
#pragma unroll
    for (int ks = 0; ks < 18; ks++) {
        bf16x8 a  = Wfv[(m * 18 + ks) * 64 + lane];
        bf16x8 b0 = *(const bf16x8*)((char*)V + pixc * VSB + ks * 64 + kq * 16);
        bf16x8 b1 = *(const bf16x8*)((char*)V + (pixc + 16) * VSB + ks * 64 + kq * 16);
        acc0 = __builtin_amdgcn_mfma_f32_16x16x32_bf16(a, b0, acc0, 0, 0, 0);
        acc1 = __builtin_amdgcn_mfma_f32_16x16x32_bf16(a, b1, acc1, 0, 0, 0);
    }

    // C/D layout: col = lane&15 -> pixel; row = (lane>>4)*4 + reg -> o
    int orow = m * 16 + kq * 4;
    float s1 = 0.0f, s2 = 0.0f;
#pragma unroll
    for (int r = 0; r < 4; r++) {
        float v0 = acc0[r];
        float v1 = acc1[r];
        size_t base = (((size_t)(b * ON + orow + r) * HN) + h) * WN + (wblk << 6);
        y[base + pixc] = v0;
        y[base + pixc + 16] = v1;
        s1 += v0 + v1;
        s2 += v0 * v0 + v1 * v1;
    }
#pragma unroll
    for (int off = 32; off > 0; off >>= 1) {
        s1 += __shfl_down(s1, off);
        s2 += __shfl_down(s2, off);
    }
    if (lane == 0) { red1[wv] = s1; red2[wv] = s2; }
    __syncthreads();
    if (threadIdx.x == 0) {
        float t1 = 0.0f, t2 = 0.0f;
#pragma unroll
        for (int i = 0; i < 8; i++) { t1 += red1[i]; t2 += red2[i]; }
        partials[blockIdx.x] = make_float2(t1, t2);
    }
}

__global__ __launch_bounds__(256) void stats_kernel(const float2* __restrict__ partials,
                                                    int nblocks,
                                                    float* __restrict__ stats) {
    __shared__ double r1[256], r2[256];
    int tid = threadIdx.x;
    double s1 = 0.0, s2 = 0.0;
    for (int i = tid; i < nblocks; i += 256) {
        s1 += (double)partials[i].x;
        s2 += (double)partials[i].y;
    }
    r1[tid] = s1;
    r2[tid] = s2;
    __syncthreads();
    for (int s = 128; s > 0; s >>= 1) {
        if (tid < s) { r1[tid] += r1[tid + s]; r2[tid] += r2[tid + s]; }
        __syncthreads();
    }
    if (tid == 0) {
        double N = (double)BN * ON * HN * WN;
        double mu = r1[0] / N;
        double var = r2[0] / N - mu * mu;
        stats[0] = (float)mu;
        stats[1] = (float)(1.0 / sqrt(var + 1e-5));
    }
}

// normalize + prak + concat(x) + 3x3/2 maxpool
__global__ __launch_bounds__(256) void out_kernel(const float* __restrict__ yb,
                                                  const float* __restrict__ x,
                                                  const float* __restrict__ stats,
                                                  float* __restrict__ out) {
    int t = blockIdx.x * 256 + threadIdx.x;
    if (t >= BN * 128 * HO * WO) return;
    int ow = t % WO;
    int oh = (t / WO) % HO;
    int ch = (t / (WO * HO)) % 128;
    int b  = t / (WO * HO * 128);

    float mu = stats[0];
    float inv = stats[1];
    float m = -INFINITY;
    if (ch < 64) {
        const float* yc = yb + ((size_t)(b * ON + ch) * HN) * WN;
#pragma unroll
        for (int dy = 0; dy < 3; dy++) {
            const float* row = yc + (2 * oh + dy) * WN + 2 * ow;
#pragma unroll
            for (int dx = 0; dx < 3; dx++) {
                float v = prak_f((row[dx] - mu) * inv);
                m = fmaxf(m, v);
            }
        }
    } else {
        const float* xc = x + ((size_t)(b * CN + (ch - 64)) * HN) * WN;
#pragma unroll
        for (int dy = 0; dy < 3; dy++) {
            const float* row = xc + (2 * oh + dy) * WN + 2 * ow;
#pragma unroll
            for (int dx = 0; dx < 3; dx++) m = fmaxf(m, row[dx]);
        }
    }
    out[t] = m;
}

extern "C" void kernel_launch(void* const* d_in, const int* in_sizes, int n_in,
                              void* d_out, int out_size, void* d_ws, size_t ws_size,
                              hipStream_t stream) {
    const float* x    = (const float*)d_in[0];
    const float* offw = (const float*)d_in[1];
    const float* offb = (const float*)d_in[2];
    const float* wgt  = (const float*)d_in[3];
    const float* mask = (const float*)d_in[4];
    float* out = (float*)d_out;

    float* ws = (float*)d_ws;
    unsigned short* Wf  = (unsigned short*)ws;            // 36864 bf16
    unsigned short* WoF = Wf + 36864;                     // 18432 bf16
    float* y  = (float*)(WoF + 18432 + 2048);             // align; 4194304 f
    float* xt = y + 4194304;                              // 4194304 f
    float2* partials = (float2*)(xt + 4194304);           // 1024 float2
    float* stats = (float*)(partials + 1024);             // 2 f

    prep_transpose_kernel<<<584, 512, 0, stream>>>(x, offw, wgt, xt, Wf, WoF);
    fused_kernel<<<1024, 512, 0, stream>>>(xt, offb, mask, WoF, Wf, y, partials);
    stats_kernel<<<1, 256, 0, stream>>>(partials, 1024, stats);
    out_kernel<<<7874, 256, 0, stream>>>(y, x, stats, out);
}

// Round 11
// 59.157 us; speedup vs baseline: 1.4279x; 1.1570x over previous
//
#include <hip/hip_runtime.h>
#include <math.h>

#define BN 4
#define CN 64
#define HN 64
#define WN 256
#define ON 64
#define NOC 18
#define PN 9
#define HO 31
#define WO 127

// LDS V: 64 pixels x 584 shorts (9 taps x 64 ch + 8 pad) = 74752 B
#define VST 584   // shorts per pixel
#define VSB 1168  // bytes per pixel

typedef __attribute__((ext_vector_type(8))) short bf16x8;
typedef __attribute__((ext_vector_type(4))) float f32x4;

__device__ __forceinline__ unsigned short f2bf(float f) {
    unsigned int u = __float_as_uint(f);
    unsigned int r = (u + 0x7fffu + ((u >> 16) & 1u)) >> 16;
    return (unsigned short)r;
}

// packed bf16 convert (RNE): low16 = bf16(lo), high16 = bf16(hi)
__device__ __forceinline__ unsigned int cvtpk(float lo, float hi) {
    unsigned int r;
    asm("v_cvt_pk_bf16_f32 %0, %1, %2" : "=v"(r) : "v"(lo), "v"(hi));
    return r;
}

__device__ __forceinline__ float trianglewave(float x) {
    const float PI_F = 3.14159274101257324f;   // float(np.pi)
    float n = floorf(x / PI_F + 0.5f);
    float m = fmodf(n, 2.0f);
    if (m < 0.0f) m += 2.0f;
    float sgn = 1.0f - 2.0f * m;
    return (x - PI_F * n) * sgn;
}

__device__ __forceinline__ float prak_f(float x) {
    const float PI_HALF = 1.57079637050628662f; // float(np.pi/2)
    return trianglewave(x) + trianglewave(x + PI_HALF);
}

// blocks 0..511: LDS-transposed x[b][c][h][w] (f32) -> x_t[b][h][w][c] (bf16)
// blocks 512..583: weight prep (Wf: 4 m-tiles, WoF: 2 m-tiles, fragment order)
__global__ __launch_bounds__(512) void prep_transpose_kernel(
        const float* __restrict__ x,
        const float* __restrict__ offw,
        const float* __restrict__ wgt,
        unsigned short* __restrict__ xt,
        unsigned short* __restrict__ Wf,
        unsigned short* __restrict__ WoF) {
    if (blockIdx.x < 512) {
        __shared__ float Tl[128][65];
        int blk = blockIdx.x;
        int whalf = blk & 1;
        int h = (blk >> 1) & 63;
        int b = blk >> 7;
        int t = threadIdx.x;
        // read: coalesced rows of x
        int fq = t & 31;           // float4 index within 128-float half row
#pragma unroll
        for (int j = 0; j < 4; j++) {
            int c = (t >> 5) + 16 * j;
            float4 v = *(const float4*)(x + ((size_t)(b * CN + c) * HN + h) * WN + whalf * 128 + fq * 4);
            Tl[fq * 4 + 0][c] = v.x;
            Tl[fq * 4 + 1][c] = v.y;
            Tl[fq * 4 + 2][c] = v.z;
            Tl[fq * 4 + 3][c] = v.w;
        }
        __syncthreads();
        // write: coalesced bf16 rows of xt (8 ch per thread = 16B)
        int cq = t & 7;
#pragma unroll
        for (int j = 0; j < 2; j++) {
            int wl = (t >> 3) + 64 * j;
            uint4 pk;
            pk.x = cvtpk(Tl[wl][cq * 8 + 0], Tl[wl][cq * 8 + 1]);
            pk.y = cvtpk(Tl[wl][cq * 8 + 2], Tl[wl][cq * 8 + 3]);
            pk.z = cvtpk(Tl[wl][cq * 8 + 4], Tl[wl][cq * 8 + 5]);
            pk.w = cvtpk(Tl[wl][cq * 8 + 6], Tl[wl][cq * 8 + 7]);
            *(uint4*)(xt + (((size_t)(b * HN) + h) * WN + whalf * 128 + wl) * 64 + cq * 8) = pk;
        }
    } else {
        int t = (blockIdx.x - 512) * 512 + threadIdx.x;
        if (t < 4 * 18 * 64 * 8) {
            int j    = t & 7;
            int lane = (t >> 3) & 63;
            int rest = t >> 9;          // 0..71
            int ks   = rest % 18;
            int m    = rest / 18;
            int o = m * 16 + (lane & 15);
            int k = ks * 32 + (lane >> 4) * 8 + j;
            int c = k & 63;
            int p = k >> 6;
            Wf[t] = f2bf(wgt[(o * CN + c) * 9 + p]);
        }
        if (t < 2 * 18 * 64 * 8) {
            int j    = t & 7;
            int lane = (t >> 3) & 63;
            int rest = t >> 9;          // 0..35
            int ks   = rest % 18;
            int mo   = rest / 18;
            int o = mo * 16 + (lane & 15);
            int k = ks * 32 + (lane >> 4) * 8 + j;
            int c = k & 63;
            int p = k >> 6;
            WoF[t] = (o < NOC) ? f2bf(offw[(o * CN + c) * 9 + p]) : (unsigned short)0;
        }
    }
}

struct TapS { float w00, w01, w10, w11; int a0, a1, a2, a3; };

// Fully fused: im2col(copy) -> offsets MFMA -> pipelined bf16 gather -> deform MFMA.
// 512 threads = 8 waves per 64-pixel tile; grid 1024 XCD-swizzled; 2 blocks/CU.
__global__ __launch_bounds__(512, 4) void fused_kernel(
        const unsigned short* __restrict__ xt,
        const float* __restrict__ offb,
        const float* __restrict__ mask,
        const unsigned short* __restrict__ WoF,
        const unsigned short* __restrict__ Wf,
        float* __restrict__ y,
        float2* __restrict__ partials) {
    __shared__ __align__(16) unsigned short V[64 * VST];   // 74752 B
    __shared__ float offs_lds[NOC * 64];                   // 4608 B
    __shared__ float red1[8], red2[8];

    int bid = blockIdx.x;
    int logical = ((bid & 7) << 7) + (bid >> 3);   // XCD-chunked
    int b = logical >> 8;
    int h = (logical >> 2) & 63;
    int wblk = logical & 3;
    int lane = threadIdx.x & 63;
    int wv = threadIdx.x >> 6;          // 0..7

    int pl = threadIdx.x >> 3;          // 0..63 (pixel, staging)
    int cg = threadIdx.x & 7;           // 0..7  (8 channels, staging)
    int w = (wblk << 6) + pl;
    const unsigned short* xb = xt + (size_t)b * HN * WN * 64;
    const uint4* xb4 = (const uint4*)xb;    // 8 uint4 per pixel row
    int kq = lane >> 4;

    // ---------- Phase 0: im2col = bf16 bit-copy ----------
#pragma unroll
    for (int p = 0; p < PN; p++) {
        int iy = h + p / 3 - 1;
        int ix = w + p % 3 - 1;
        uint4 pk = {0u, 0u, 0u, 0u};
        if (iy >= 0 && iy < HN && ix >= 0 && ix < WN)
            pk = xb4[((size_t)iy * WN + ix) * 8 + cg];
        *(uint4*)((char*)V + pl * VSB + p * 128 + cg * 16) = pk;
    }
    __syncthreads();

    // ---------- Offsets MFMA: 18x576 @ 576x64 ----------
    {
        int mo = wv >> 2;       // 0..1
        int nt = wv & 3;        // 0..3
        f32x4 acc = {0.0f, 0.0f, 0.0f, 0.0f};
        const bf16x8* Wov = (const bf16x8*)WoF;
        int pixc = nt * 16 + (lane & 15);
#pragma unroll
        for (int ks = 0; ks < 18; ks++) {
            bf16x8 a = Wov[(mo * 18 + ks) * 64 + lane];
            bf16x8 bfr = *(const bf16x8*)((char*)V + pixc * VSB + ks * 64 + kq * 16);
            acc = __builtin_amdgcn_mfma_f32_16x16x32_bf16(a, bfr, acc, 0, 0, 0);
        }
        int ocb = mo * 16 + kq * 4;
#pragma unroll
        for (int r = 0; r < 4; r++) {
            int oc = ocb + r;
            if (oc < NOC) offs_lds[oc * 64 + pixc] = acc[r] + offb[oc];
        }
    }
    __syncthreads();

    // ---------- Phase 1: bf16 gather (2-deep pipelined, overwrites V) ----------
    {
        float mkv[9];
#pragma unroll
        for (int p = 0; p < 9; p++) mkv[p] = mask[((b * PN + p) * HN + h) * WN + w];

        auto stage = [&](int p) -> TapS {
            TapS s;
            float offy = offs_lds[(2 * p) * 64 + pl];
            float offx = offs_lds[(2 * p + 1) * 64 + pl];
            float mk = mkv[p];
            float py = (float)(h + p / 3) + offy;   // padded space
            float px = (float)(w + p % 3) + offx;
            float fy0 = floorf(py), fx0 = floorf(px);
            float wy1 = py - fy0, wx1 = px - fx0;
            float wy0 = 1.0f - wy1, wx0 = 1.0f - wx1;
            int iy0 = (int)fy0 - 1, ix0 = (int)fx0 - 1;
            int iy1 = iy0 + 1, ix1 = ix0 + 1;
            bool vy0 = (iy0 >= 0) && (iy0 < HN);
            bool vy1 = (iy1 >= 0) && (iy1 < HN);
            bool vx0 = (ix0 >= 0) && (ix0 < WN);
            bool vx1 = (ix1 >= 0) && (ix1 < WN);
            s.w00 = (vy0 && vx0) ? wy0 * wx0 * mk : 0.0f;
            s.w01 = (vy0 && vx1) ? wy0 * wx1 * mk : 0.0f;
            s.w10 = (vy1 && vx0) ? wy1 * wx0 * mk : 0.0f;
            s.w11 = (vy1 && vx1) ? wy1 * wx1 * mk : 0.0f;
            int cy0 = min(max(iy0, 0), HN - 1), cy1 = min(max(iy1, 0), HN - 1);
            int cx0 = min(max(ix0, 0), WN - 1), cx1 = min(max(ix1, 0), WN - 1);
            s.a0 = (cy0 * WN + cx0) * 8 + cg;
            s.a1 = (cy0 * WN + cx1) * 8 + cg;
            s.a2 = (cy1 * WN + cx0) * 8 + cg;
            s.a3 = (cy1 * WN + cx1) * 8 + cg;
            return s;
        };

        TapS sC = stage(0);
        uint4 A = xb4[sC.a0], B = xb4[sC.a1], C = xb4[sC.a2], D = xb4[sC.a3];

#pragma unroll
        for (int p = 0; p < 9; p++) {
            TapS sN;
            uint4 nA, nB, nC, nD;
            if (p < 8) {
                sN = stage(p + 1);
                nA = xb4[sN.a0]; nB = xb4[sN.a1];
                nC = xb4[sN.a2]; nD = xb4[sN.a3];
            }
            // unpack bf16 pairs -> f32 (exact: <<16)
            float fa[8], fb[8], fc[8], fd[8];
            {
                unsigned int ua[4] = {A.x, A.y, A.z, A.w};
                unsigned int ub[4] = {B.x, B.y, B.z, B.w};
                unsigned int uc[4] = {C.x, C.y, C.z, C.w};
                unsigned int ud[4] = {D.x, D.y, D.z, D.w};
#pragma unroll
                for (int j = 0; j < 4; j++) {
                    fa[2 * j] = __uint_as_float(ua[j] << 16);
                    fa[2 * j + 1] = __uint_as_float(ua[j] & 0xffff0000u);
                    fb[2 * j] = __uint_as_float(ub[j] << 16);
                    fb[2 * j + 1] = __uint_as_float(ub[j] & 0xffff0000u);
                    fc[2 * j] = __uint_as_float(uc[j] << 16);
                    fc[2 * j + 1] = __uint_as_float(uc[j] & 0xffff0000u);
                    fd[2 * j] = __uint_as_float(ud[j] << 16);
                    fd[2 * j + 1] = __uint_as_float(ud[j] & 0xffff0000u);
                }
            }
            float v[8];
#pragma unroll
            for (int j = 0; j < 8; j++)
                v[j] = sC.w00 * fa[j] + sC.w01 * fb[j] + sC.w10 * fc[j] + sC.w11 * fd[j];
            uint4 pk;
            pk.x = cvtpk(v[0], v[1]);
            pk.y = cvtpk(v[2], v[3]);
            pk.z = cvtpk(v[4], v[5]);
            pk.w = cvtpk(v[6], v[7]);
            *(uint4*)((char*)V + pl * VSB + p * 128 + cg * 16) = pk;
            if (p < 8) {
                sC = sN;
                A = nA; B = nB; C = nC; D = nD;
            }
        }
    }
    __syncthreads();

    // ---------- Phase 2: deform MFMA ----------
    int m = wv >> 1;            // M-tile 0..3
    int npair = wv & 1;         // N-tiles npair*2, npair*2+1
    f32x4 acc0 = {0.0f, 0.0f, 0.0f, 0.0f};
    f32x4 acc1 = {0.0f, 0.0f, 0.0f, 0.0f};
    const bf16x8* Wfv = (const bf16x8*)Wf;
    int pixc = npair * 32 + (lane & 15);
#pragma unroll
    for (int ks = 0; ks < 18; ks++) {
        bf16x8 a  = Wfv[(m * 18 + ks) * 64 + lane];
        bf16x8 b0 = *(const bf16x8*)((char*)V + pixc * VSB + ks * 64 + kq * 16);
        bf16x8 b1 = *(const bf16x8*)((char*)V + (pixc + 16) * VSB + ks * 64 + kq * 16);
        acc0 = __builtin_amdgcn_mfma_f32_16x16x32_bf16(a, b0, acc0, 0, 0, 0);
        acc1 = __builtin_amdgcn_mfma_f32_16x16x32_bf16(a, b1, acc1, 0, 0, 0);
    }

    // C/D layout: col = lane&15 -> pixel; row = (lane>>4)*4 + reg -> o
    int orow = m * 16 + kq * 4;
    float s1 = 0.0f, s2 = 0.0f;
#pragma unroll
    for (int r = 0; r < 4; r++) {
        float v0 = acc0[r];
        float v1 = acc1[r];
        size_t base = (((size_t)(b * ON + orow + r) * HN) + h) * WN + (wblk << 6);
        y[base + pixc] = v0;
        y[base + pixc + 16] = v1;
        s1 += v0 + v1;
        s2 += v0 * v0 + v1 * v1;
    }
#pragma unroll
    for (int off = 32; off > 0; off >>= 1) {
        s1 += __shfl_down(s1, off);
        s2 += __shfl_down(s2, off);
    }
    if (lane == 0) { red1[wv] = s1; red2[wv] = s2; }
    __syncthreads();
    if (threadIdx.x == 0) {
        float t1 = 0.0f, t2 = 0.0f;
#pragma unroll
        for (int i = 0; i < 8; i++) { t1 += red1[i]; t2 += red2[i]; }
        partials[blockIdx.x] = make_float2(t1, t2);
    }
}

__global__ __launch_bounds__(256) void stats_kernel(const float2* __restrict__ partials,
                                                    int nblocks,
                                                    float* __restrict__ stats) {
    __shared__ double r1[256], r2[256];
    int tid = threadIdx.x;
    double s1 = 0.0, s2 = 0.0;
    for (int i = tid; i < nblocks; i += 256) {
        s1 += (double)partials[i].x;
        s2 += (double)partials[i].y;
    }
    r1[tid] = s1;
    r2[tid] = s2;
    __syncthreads();
    for (int s = 128; s > 0; s >>= 1) {
        if (tid < s) { r1[tid] += r1[tid + s]; r2[tid] += r2[tid + s]; }
        __syncthreads();
    }
    if (tid == 0) {
        double N = (double)BN * ON * HN * WN;
        double mu = r1[0] / N;
        double var = r2[0] / N - mu * mu;
        stats[0] = (float)mu;
        stats[1] = (float)(1.0 / sqrt(var + 1e-5));
    }
}

// normalize + prak + concat(x) + 3x3/2 maxpool
__global__ __launch_bounds__(256) void out_kernel(const float* __restrict__ yb,
                                                  const float* __restrict__ x,
                                                  const float* __restrict__ stats,
                                                  float* __restrict__ out) {
    int t = blockIdx.x * 256 + threadIdx.x;
    if (t >= BN * 128 * HO * WO) return;
    int ow = t % WO;
    int oh = (t / WO) % HO;
    int ch = (t / (WO * HO)) % 128;
    int b  = t / (WO * HO * 128);

    float mu = stats[0];
    float inv = stats[1];
    float m = -INFINITY;
    if (ch < 64) {
        const float* yc = yb + ((size_t)(b * ON + ch) * HN) * WN;
#pragma unroll
        for (int dy = 0; dy < 3; dy++) {
            const float* row = yc + (2 * oh + dy) * WN + 2 * ow;
#pragma unroll
            for (int dx = 0; dx < 3; dx++) {
                float v = prak_f((row[dx] - mu) * inv);
                m = fmaxf(m, v);
            }
        }
    } else {
        const float* xc = x + ((size_t)(b * CN + (ch - 64)) * HN) * WN;
#pragma unroll
        for (int dy = 0; dy < 3; dy++) {
            const float* row = xc + (2 * oh + dy) * WN + 2 * ow;
#pragma unroll
            for (int dx = 0; dx < 3; dx++) m = fmaxf(m, row[dx]);
        }
    }
    out[t] = m;
}

extern "C" void kernel_launch(void* const* d_in, const int* in_sizes, int n_in,
                              void* d_out, int out_size, void* d_ws, size_t ws_size,
                              hipStream_t stream) {
    const float* x    = (const float*)d_in[0];
    const float* offw = (const float*)d_in[1];
    const float* offb = (const float*)d_in[2];
    const float* wgt  = (const float*)d_in[3];
    const float* mask = (const float*)d_in[4];
    float* out = (float*)d_out;

    unsigned short* Wf  = (unsigned short*)d_ws;          // 36864 bf16
    unsigned short* WoF = Wf + 36864;                     // 18432 bf16
    float* y  = (float*)(WoF + 18432);                    // 110592B offset; 4194304 f
    unsigned short* xt = (unsigned short*)(y + 4194304);  // 4194304 bf16
    float2* partials = (float2*)(xt + 4194304);           // 1024 float2
    float* stats = (float*)(partials + 1024);             // 2 f

    prep_transpose_kernel<<<584, 512, 0, stream>>>(x, offw, wgt, xt, Wf, WoF);
    fused_kernel<<<1024, 512, 0, stream>>>(xt, offb, mask, WoF, Wf, y, partials);
    stats_kernel<<<1, 256, 0, stream>>>(partials, 1024, stats);
    out_kernel<<<7874, 256, 0, stream>>>(y, x, stats, out);
}